// Round 6
// baseline (428.020 us; speedup 1.0000x reference)
//
#include <hip/hip_runtime.h>
#include <hip/hip_cooperative_groups.h>
#include <math.h>
#include <stdint.h>

namespace cg = cooperative_groups;

#define N512 512

typedef __attribute__((ext_vector_type(8))) short short8;
typedef __attribute__((ext_vector_type(4))) float floatx4;

__device__ __forceinline__ short f2bf(float f) {
    uint32_t u = __float_as_uint(f);
    uint32_t r = u + 0x7fffu + ((u >> 16) & 1u);
    return (short)(r >> 16);
}

// cheap round-half-up (2 VALU): fine vs 0.109 threshold
__device__ __forceinline__ short f2bf_fast(float f) {
    return (short)((__float_as_uint(f) + 0x8000u) >> 16);
}

__device__ __forceinline__ void gload_lds16(const void* g, void* l) {
    __builtin_amdgcn_global_load_lds(
        (const __attribute__((address_space(1))) void*)g,
        (__attribute__((address_space(3))) void*)l,
        16, 0, 0);
}

// XCD-sibling decode (verified R2: halved FETCH): per 32 consecutive tile
// ids = 8 (x,z) pairs x their 4 y-siblings; siblings 8 apart -> same XCD.
// Fallback to plain decode when c is odd.
__device__ __forceinline__ void decode_swz(int L, int c,
                                           int& bx, int& by, int& bz) {
    if (c & 1) {
        bx = L & 3; by = (L >> 2) & 3; bz = L >> 4;
    } else {
        const int g = L >> 5, s = L & 31;
        const int u = (g << 3) | (s & 7);
        by = s >> 3; bx = u & 3; bz = u >> 2;
    }
}

// ---------------------------------------------------------------------------
// Stage-1 tile (R0-verified body): Tt[z][n][h] = sum_k M[n,k] * X[z][h,k]
// 128x128 tile, BK=64, 4 waves, single 32KB LDS buffer, fused fp32->bf16 cvt.
// ---------------------------------------------------------------------------
__device__ __forceinline__ void s1_tile(short* lds, const short* __restrict__ A,
                                        const float* __restrict__ Xg,
                                        short* __restrict__ Tg,
                                        int tile, int c) {
    short* ldsA = lds;
    short* ldsB = lds + 8192;

    const int t = threadIdx.x;
    const int w = t >> 6;          // wave 0..3
    const int l = t & 63;
    const int q = (t >> 4) & 3;
    const int r = t & 15;

    int bx, by, bz;
    decode_swz(tile, c, bx, by, bz);
    const int bm0 = by * 128;      // A rows (n)
    const int bn0 = bx * 128;      // B rows (h)
    const int wm0 = (w >> 1) * 64;
    const int wn0 = (w & 1) * 64;

    const float* Xs = Xg + ((long)bz << 18);
    short* Tt = Tg + ((long)bz << 18);

    const int rsub = l >> 3;                 // row within 8-row chunk
    const int glog = (l & 7) ^ rsub;         // pre-swizzled 16B granule

    const int brow = t >> 4;                 // 0..15
    const int col4 = t & 15;
    const int bg   = col4 >> 1;
    const int bh   = col4 & 1;

    floatx4 acc[4][4] = {};

    for (int kt = 0; kt < 8; ++kt) {
        const int k0 = kt * 64;
#pragma unroll
        for (int i = 0; i < 4; ++i) {
            const int ch = w * 4 + i;
            const int rt = ch * 8 + rsub;
            gload_lds16(A + (((long)(bm0 + rt)) << 9) + k0 + glog * 8,
                        ldsA + ch * 512);
        }
        float4 v[8];
#pragma unroll
        for (int p = 0; p < 8; ++p) {
            const int rt = p * 16 + brow;
            v[p] = *(const float4*)(Xs + (((long)(bn0 + rt)) << 9) + k0 + col4 * 4);
        }
#pragma unroll
        for (int p = 0; p < 8; ++p) {
            const int rt = p * 16 + brow;
            const int bch = rt >> 3;
            const int brs = rt & 7;
            short4 o;
            o.x = f2bf_fast(v[p].x);
            o.y = f2bf_fast(v[p].y);
            o.z = f2bf_fast(v[p].z);
            o.w = f2bf_fast(v[p].w);
            *(short4*)(ldsB + bch * 512 + brs * 64 + ((bg ^ brs) * 8) + bh * 4) = o;
        }
        __syncthreads();
#pragma unroll
        for (int kk = 0; kk < 2; ++kk) {
            const int cc = kk * 4 + q;
            const int goff = ((cc ^ (r & 7)) * 8);
            short8 af[4], bfr[4];
#pragma unroll
            for (int i = 0; i < 4; ++i) {
                af[i]  = *(const short8*)(ldsA + (wm0 + i * 16 + r) * 64 + goff);
                bfr[i] = *(const short8*)(ldsB + (wn0 + i * 16 + r) * 64 + goff);
            }
#pragma unroll
            for (int i = 0; i < 4; ++i)
#pragma unroll
                for (int j = 0; j < 4; ++j)
                    acc[i][j] = __builtin_amdgcn_mfma_f32_16x16x32_bf16(
                        af[i], bfr[j], acc[i][j], 0, 0, 0);
        }
        __syncthreads();
    }

#pragma unroll
    for (int i = 0; i < 4; ++i) {
        const int mrow = bm0 + wm0 + i * 16 + q * 4;
#pragma unroll
        for (int j = 0; j < 4; ++j) {
            const int ncol = bn0 + wn0 + j * 16 + r;
#pragma unroll
            for (int rg = 0; rg < 4; ++rg)
                Tt[(long)(mrow + rg) * N512 + ncol] = f2bf(acc[i][j][rg]);
        }
    }
}

// ---------------------------------------------------------------------------
// Stage-2 tile (R0-verified body): Out[z][m][n] = sum_h M[m,h] * Tt[z][n,h]
// ---------------------------------------------------------------------------
__device__ __forceinline__ void s2_tile(short* lds, const short* __restrict__ A,
                                        const short* __restrict__ Bg,
                                        float* __restrict__ Cg,
                                        int tile, int c) {
    short* ldsA = lds;
    short* ldsB = lds + 8192;

    const int t = threadIdx.x;
    const int w = t >> 6;
    const int l = t & 63;
    const int q = (t >> 4) & 3;
    const int r = t & 15;

    const int bx = tile & 3;
    const int by = (tile >> 2) & 3;
    const int bz = tile >> 4;
    const int bm0 = by * 128;
    const int bn0 = bx * 128;
    const int wm0 = (w >> 1) * 64;
    const int wn0 = (w & 1) * 64;

    const short* Bs = Bg + ((long)bz << 18);
    float* C = Cg + ((long)bz << 18);

    const int rsub = l >> 3;
    const int glog = (l & 7) ^ rsub;

    floatx4 acc[4][4] = {};

    for (int kt = 0; kt < 8; ++kt) {
        const int k0 = kt * 64;
#pragma unroll
        for (int i = 0; i < 4; ++i) {
            const int ch = w * 4 + i;
            const int rt = ch * 8 + rsub;
            gload_lds16(A + (((long)(bm0 + rt)) << 9) + k0 + glog * 8,
                        ldsA + ch * 512);
            gload_lds16(Bs + (((long)(bn0 + rt)) << 9) + k0 + glog * 8,
                        ldsB + ch * 512);
        }
        __syncthreads();
#pragma unroll
        for (int kk = 0; kk < 2; ++kk) {
            const int cc = kk * 4 + q;
            const int goff = ((cc ^ (r & 7)) * 8);
            short8 af[4], bfr[4];
#pragma unroll
            for (int i = 0; i < 4; ++i) {
                af[i]  = *(const short8*)(ldsA + (wm0 + i * 16 + r) * 64 + goff);
                bfr[i] = *(const short8*)(ldsB + (wn0 + i * 16 + r) * 64 + goff);
            }
#pragma unroll
            for (int i = 0; i < 4; ++i)
#pragma unroll
                for (int j = 0; j < 4; ++j)
                    acc[i][j] = __builtin_amdgcn_mfma_f32_16x16x32_bf16(
                        af[i], bfr[j], acc[i][j], 0, 0, 0);
        }
        __syncthreads();
    }

#pragma unroll
    for (int i = 0; i < 4; ++i) {
        const int mrow = bm0 + wm0 + i * 16 + q * 4;
#pragma unroll
        for (int j = 0; j < 4; ++j) {
            const int ncol = bn0 + wn0 + j * 16 + r;
#pragma unroll
            for (int rg = 0; rg < 4; ++rg)
                C[(long)(mrow + rg) * N512 + ncol] = acc[i][j][rg];
        }
    }
}

// ---------------------------------------------------------------------------
// Fused cooperative kernel: build M | grid.sync | all s1 tiles | grid.sync |
// all s2 tiles. One dispatch per iteration -> no inter-kernel gaps/drain.
// ---------------------------------------------------------------------------
__global__ __launch_bounds__(256) void idct_fused(short* __restrict__ Mb,
                                                  const float* __restrict__ X,
                                                  short* __restrict__ Tt,
                                                  float* __restrict__ out,
                                                  int c) {
    __shared__ __align__(16) short lds[2 * 8192];   // 32 KB
    cg::grid_group grid = cg::this_grid();
    const int nb = (int)gridDim.x;
    const int bid = (int)blockIdx.x;
    const int t = (int)threadIdx.x;

    // phase 0: build M[n,k] = s_k * cos(pi*k*(2n+1)/(2N)), bf16
    for (int idx = bid * 256 + t; idx < N512 * N512; idx += nb * 256) {
        int n = idx >> 9;
        int k = idx & 511;
        int j = (k * (2 * n + 1)) & (4 * N512 - 1);
        float theta = (float)j * (3.14159265358979323846f / (2.0f * (float)N512));
        float s = (k == 0) ? 0.044194173824159216f : 0.0625f;
        Mb[idx] = f2bf(s * cosf(theta));
    }
    __threadfence();
    grid.sync();
    __threadfence();

    const int ntile = 16 * c;
    // phase 1: all stage-1 tiles (grid-stride)
    for (int tile = bid; tile < ntile; tile += nb)
        s1_tile(lds, Mb, X, Tt, tile, c);

    __threadfence();
    grid.sync();
    __threadfence();

    // phase 2: all stage-2 tiles (grid-stride)
    for (int tile = bid; tile < ntile; tile += nb)
        s2_tile(lds, Mb, Tt, out, tile, c);
}

extern "C" void kernel_launch(void* const* d_in, const int* in_sizes, int n_in,
                              void* d_out, int out_size, void* d_ws, size_t ws_size,
                              hipStream_t stream) {
    const float* X = (const float*)d_in[0];
    float* out = (float*)d_out;

    const long plane = (long)N512 * N512;          // 262144
    const int slices = in_sizes[0] / (int)plane;   // 96

    short* Mb = (short*)d_ws;                      // 512 KB
    short* Tt = Mb + plane;                        // chunk * plane bf16

    long avail = (long)ws_size - plane * 2;        // bytes after M
    int chunk = (int)(avail / (plane * 2));        // bf16 plane per slice
    if (chunk > slices) chunk = slices;
    if (chunk < 1) chunk = 1;

    // co-resident grid size, cached (queries only; no alloc/sync)
    static int s_blocks = 0;
    if (s_blocks == 0) {
        int nbpcu = 0;
        if (hipOccupancyMaxActiveBlocksPerMultiprocessor(
                &nbpcu, idct_fused, 256, 0) != hipSuccess || nbpcu < 1)
            nbpcu = 2;   // conservative fallback (32 KB LDS -> >=2 always)
        hipDeviceProp_t prop;
        int dev = 0;
        int ncu = 256;
        if (hipGetDevice(&dev) == hipSuccess &&
            hipGetDeviceProperties(&prop, dev) == hipSuccess)
            ncu = prop.multiProcessorCount;
        long g = (long)nbpcu * ncu;
        if (g > 1536) g = 1536;
        if (g < 64) g = 64;
        s_blocks = (int)g;
    }

    for (int s0 = 0; s0 < slices; s0 += chunk) {
        int c = (s0 + chunk <= slices) ? chunk : (slices - s0);
        int g = s_blocks;
        if (g > 16 * c) g = 16 * c;
        const float* Xp = X + (long)s0 * plane;
        float* op = out + (long)s0 * plane;
        void* args[] = {(void*)&Mb, (void*)&Xp, (void*)&Tt, (void*)&op, (void*)&c};
        hipLaunchCooperativeKernel((void*)idct_fused, dim3(g), dim3(256),
                                   args, 0, stream);
    }
}

// Round 8
// 279.976 us; speedup vs baseline: 1.5288x; 1.5288x over previous
//
#include <hip/hip_runtime.h>
#include <math.h>
#include <stdint.h>

#define N512 512

typedef __attribute__((ext_vector_type(8))) short short8;
typedef __attribute__((ext_vector_type(4))) float floatx4;

__device__ __forceinline__ short f2bf(float f) {
    uint32_t u = __float_as_uint(f);
    uint32_t r = u + 0x7fffu + ((u >> 16) & 1u);
    return (short)(r >> 16);
}

// cheap round-half-up (2 VALU): fine vs 0.109 threshold
__device__ __forceinline__ short f2bf_fast(float f) {
    return (short)((__float_as_uint(f) + 0x8000u) >> 16);
}

__device__ __forceinline__ void gload_lds16(const void* g, void* l) {
    __builtin_amdgcn_global_load_lds(
        (const __attribute__((address_space(1))) void*)g,
        (__attribute__((address_space(3))) void*)l,
        16, 0, 0);
}

// M[n,k] = s_k * cos(pi * k * (2n+1) / (2N)), bf16 (RNE-ish)
__global__ __launch_bounds__(256) void build_idct_matrix_bf16(short* __restrict__ M) {
    int idx = blockIdx.x * 256 + threadIdx.x;
    int n = idx >> 9;
    int k = idx & 511;
    int j = (k * (2 * n + 1)) & (4 * N512 - 1);
    float theta = (float)j * (3.14159265358979323846f / (2.0f * (float)N512));
    float s = (k == 0) ? 0.044194173824159216f : 0.0625f;
    M[idx] = f2bf(s * cosf(theta));
}

// ---------------------------------------------------------------------------
// Stage 1, READ-ONCE tiling: Tt[z][n][h] = sum_k M[n,k] * X[z][h,k]
// Block = ALL 512 n-rows x 64-h strip. X rows of this strip are read exactly
// ONCE per slice (kills the x4 L3 re-read that pinned s1 at 70us). M (512KB)
// is staged fully by every block but is L2-resident per XCD (fast re-read).
// 4 waves; wave w covers n in [w*128, w*128+128) -> acc[8][4] (R4-verified).
// LDS 72KB: A-strip 512x64 (64KB) + X-tile 64x64 bf16 (8KB). 2 blocks/CU.
// All swizzle/fragment math = R0-verified formulas (row range extended).
// ---------------------------------------------------------------------------
__global__ __launch_bounds__(256) void gemm_s1(const short* __restrict__ A,
                                               const float* __restrict__ Xg,
                                               short* __restrict__ Tg) {
    __shared__ __align__(16) short lds[36864];   // A 32768 | B 4096 shorts
    short* ldsA = lds;
    short* ldsB = lds + 32768;

    const int t = threadIdx.x;
    const int w = t >> 6;          // wave 0..3
    const int l = t & 63;
    const int q = (l >> 4) & 3;
    const int r = l & 15;

    const int h0 = blockIdx.x * 64;              // h-strip
    const float* Xs = Xg + ((long)blockIdx.y << 18);
    short* Tt = Tg + ((long)blockIdx.y << 18);

    // A-DMA mapping (verified): chunk = 8 rows; lane covers row l>>3,
    // pre-swizzled granule (l&7)^(l>>3) on the global address.
    const int rsub = l >> 3;
    const int glog = (l & 7) ^ rsub;

    // X staging: pass p: row rt = p*16 + (t>>4); float4 at col (t&15)*4
    const int brow = t >> 4;                     // 0..15
    const int col4 = t & 15;
    const int bg   = col4 >> 1;
    const int bh   = col4 & 1;

    const int wm0 = w * 128;                     // wave's n-base

    floatx4 acc[8][4] = {};

    for (int kt = 0; kt < 8; ++kt) {
        const int k0 = kt * 64;
        // A: full 512-row strip of M, 64 chunks, 16 per wave (DMA)
#pragma unroll
        for (int i = 0; i < 16; ++i) {
            const int ch = w * 16 + i;
            gload_lds16(A + (((long)(ch * 8 + rsub)) << 9) + k0 + glog * 8,
                        ldsA + ch * 512);
        }
        // X: 64 rows x 64 cols fp32, 4 coalesced float4 passes
        float4 v[4];
#pragma unroll
        for (int p = 0; p < 4; ++p) {
            const int rt = p * 16 + brow;
            v[p] = *(const float4*)(Xs + (((long)(h0 + rt)) << 9) + k0 + col4 * 4);
        }
        // cvt -> bf16, swizzled ds_write (same formula as ever)
#pragma unroll
        for (int p = 0; p < 4; ++p) {
            const int rt = p * 16 + brow;
            short4 o;
            o.x = f2bf_fast(v[p].x);
            o.y = f2bf_fast(v[p].y);
            o.z = f2bf_fast(v[p].z);
            o.w = f2bf_fast(v[p].w);
            *(short4*)(ldsB + rt * 64 + ((bg ^ (rt & 7)) * 8) + bh * 4) = o;
        }
        __syncthreads();   // drains vmcnt(0): A-DMA + v landed
#pragma unroll
        for (int kk = 0; kk < 2; ++kk) {
            const int cc = kk * 4 + q;
            const int goff = ((cc ^ (r & 7)) * 8);
            short8 bfr[4];
#pragma unroll
            for (int nf = 0; nf < 4; ++nf)
                bfr[nf] = *(const short8*)(ldsB + (nf * 16 + r) * 64 + goff);
#pragma unroll
            for (int mf = 0; mf < 8; ++mf) {
                short8 af = *(const short8*)(ldsA + (wm0 + mf * 16 + r) * 64 + goff);
#pragma unroll
                for (int nf = 0; nf < 4; ++nf)
                    acc[mf][nf] = __builtin_amdgcn_mfma_f32_16x16x32_bf16(
                        af, bfr[nf], acc[mf][nf], 0, 0, 0);
            }
        }
        __syncthreads();
    }

    // epilogue: n-row = wm0 + mf*16 + q*4 + rg, h-col = h0 + nf*16 + r
#pragma unroll
    for (int mf = 0; mf < 8; ++mf) {
        const int nrow = wm0 + mf * 16 + q * 4;
#pragma unroll
        for (int nf = 0; nf < 4; ++nf) {
            const int hcol = h0 + nf * 16 + r;
#pragma unroll
            for (int rg = 0; rg < 4; ++rg)
                Tt[(long)(nrow + rg) * N512 + hcol] = f2bf(acc[mf][nf][rg]);
        }
    }
}

// ---------------------------------------------------------------------------
// Stage 2, READ-ONCE tiling: Out[z][m][n] = sum_h M[m,h] * Tt[z][n,h]
// Block = ALL 512 m-rows x 64-n strip; Tt rows of the strip read ONCE.
// Both operands via DMA. Same geometry/LDS as s1.
// ---------------------------------------------------------------------------
__global__ __launch_bounds__(256) void gemm_s2(const short* __restrict__ A,
                                               const short* __restrict__ Bg,
                                               float* __restrict__ Cg) {
    __shared__ __align__(16) short lds[36864];
    short* ldsA = lds;
    short* ldsB = lds + 32768;

    const int t = threadIdx.x;
    const int w = t >> 6;
    const int l = t & 63;
    const int q = (l >> 4) & 3;
    const int r = l & 15;

    const int n0 = blockIdx.x * 64;              // n-strip (rows of Tt)
    const short* Bs = Bg + ((long)blockIdx.y << 18);
    float* C = Cg + ((long)blockIdx.y << 18);

    const int rsub = l >> 3;
    const int glog = (l & 7) ^ rsub;

    const int wm0 = w * 128;

    floatx4 acc[8][4] = {};

    for (int kt = 0; kt < 8; ++kt) {
        const int k0 = kt * 64;
        // A: 64 chunks (full M strip), 16/wave; B: 8 chunks (64 Tt rows), 2/wave
#pragma unroll
        for (int i = 0; i < 16; ++i) {
            const int ch = w * 16 + i;
            gload_lds16(A + (((long)(ch * 8 + rsub)) << 9) + k0 + glog * 8,
                        ldsA + ch * 512);
        }
#pragma unroll
        for (int i = 0; i < 2; ++i) {
            const int ch = w * 2 + i;
            gload_lds16(Bs + (((long)(n0 + ch * 8 + rsub)) << 9) + k0 + glog * 8,
                        ldsB + ch * 512);
        }
        __syncthreads();   // drains vmcnt(0)
#pragma unroll
        for (int kk = 0; kk < 2; ++kk) {
            const int cc = kk * 4 + q;
            const int goff = ((cc ^ (r & 7)) * 8);
            short8 bfr[4];
#pragma unroll
            for (int nf = 0; nf < 4; ++nf)
                bfr[nf] = *(const short8*)(ldsB + (nf * 16 + r) * 64 + goff);
#pragma unroll
            for (int mf = 0; mf < 8; ++mf) {
                short8 af = *(const short8*)(ldsA + (wm0 + mf * 16 + r) * 64 + goff);
#pragma unroll
                for (int nf = 0; nf < 4; ++nf)
                    acc[mf][nf] = __builtin_amdgcn_mfma_f32_16x16x32_bf16(
                        af, bfr[nf], acc[mf][nf], 0, 0, 0);
            }
        }
        __syncthreads();
    }

    // epilogue: m-row = wm0 + mf*16 + q*4 + rg, n-col = n0 + nf*16 + r (fp32)
#pragma unroll
    for (int mf = 0; mf < 8; ++mf) {
        const int mrow = wm0 + mf * 16 + q * 4;
#pragma unroll
        for (int nf = 0; nf < 4; ++nf) {
            const int ncol = n0 + nf * 16 + r;
#pragma unroll
            for (int rg = 0; rg < 4; ++rg)
                C[(long)(mrow + rg) * N512 + ncol] = acc[mf][nf][rg];
        }
    }
}

extern "C" void kernel_launch(void* const* d_in, const int* in_sizes, int n_in,
                              void* d_out, int out_size, void* d_ws, size_t ws_size,
                              hipStream_t stream) {
    const float* X = (const float*)d_in[0];
    float* out = (float*)d_out;

    const long plane = (long)N512 * N512;          // 262144
    const int slices = in_sizes[0] / (int)plane;   // 96

    short* Mb = (short*)d_ws;                      // 512 KB
    short* Tt = Mb + plane;                        // chunk * plane bf16

    long avail = (long)ws_size - plane * 2;        // bytes after M
    int chunk = (int)(avail / (plane * 2));        // bf16 plane per slice
    if (chunk > slices) chunk = slices;
    if (chunk < 1) chunk = 1;

    build_idct_matrix_bf16<<<dim3((int)(plane / 256)), dim3(256), 0, stream>>>(Mb);

    for (int s0 = 0; s0 < slices; s0 += chunk) {
        int c = (s0 + chunk <= slices) ? chunk : (slices - s0);
        // stage 1 (reads fp32 X directly): Tt[z][n][h] = sum_k M[n,k]*X[z][h,k]
        gemm_s1<<<dim3(8, c), dim3(256), 0, stream>>>(
            Mb, X + (long)s0 * plane, Tt);
        // stage 2: Out[z][m][n] = sum_h M[m,h]*Tt[z][n,h]
        gemm_s2<<<dim3(8, c), dim3(256), 0, stream>>>(
            Mb, Tt, out + (long)s0 * plane);
    }
}